// Round 21
// baseline (306.302 us; speedup 1.0000x reference)
//
#include <hip/hip_runtime.h>

#define NN 200000
#define NE 5000000
#define DIN 128
#define HID 16
#define DOUT 2
#define BSZ 391          // dst-buckets of 391 nodes: 512 buckets exactly
#define NB 512           // 2 blocks/CU on 256 CUs -> full occupancy, exact balance
#define LBITS 9          // local dst index bits (391 < 512)
#define NCH 4            // src slices of 50000 nodes (3.2 MB of xs' @ HID=16, fits L2)
#define SLICE_DIV 50000
#define NK (NB * NCH)    // 2048 (bucket,slice) segments for rowStart
#define NKB 512          // stage-1 sort keys = buckets only
#define SKEYS 2048       // subsort keys: (slice<<9)|dst_local
#define PB 512           // partition grid blocks (2/CU -> 16 waves)
#define PT 512           // partition block threads
#define ECAP 9216        // subsort LDS edge cache (mean segment 9766, 94% coverage)

static_assert((size_t)NB * BSZ >= NN, "bucket coverage");
static_assert((NN - 1) / SLICE_DIV == NCH - 1, "slice count");
static_assert(NE % 8 == 0, "int4-pair edge reads");

// ---------------- stage 1: counting sort by bucket = dst/391 (512 keys) ----------------
// 8 edges per iteration: 8 independent atomic/store chains (latency-bound fix).

__global__ __launch_bounds__(PT) void hist_pass(const int4* __restrict__ dst4,
                                                int* __restrict__ blockHist) {
    __shared__ int h[NKB];  // 2 KB
    for (int k = threadIdx.x; k < NKB; k += PT) h[k] = 0;
    __syncthreads();
    const int NI8 = NE / 8;
    for (int j = blockIdx.x * PT + threadIdx.x; j < NI8; j += PB * PT) {
        int4 d0 = dst4[2 * j];
        int4 d1 = dst4[2 * j + 1];
        atomicAdd(&h[d0.x / BSZ], 1);
        atomicAdd(&h[d0.y / BSZ], 1);
        atomicAdd(&h[d0.z / BSZ], 1);
        atomicAdd(&h[d0.w / BSZ], 1);
        atomicAdd(&h[d1.x / BSZ], 1);
        atomicAdd(&h[d1.y / BSZ], 1);
        atomicAdd(&h[d1.z / BSZ], 1);
        atomicAdd(&h[d1.w / BSZ], 1);
    }
    __syncthreads();
    for (int k = threadIdx.x; k < NKB; k += PT)
        blockHist[(size_t)blockIdx.x * NKB + k] = h[k];
}

__global__ __launch_bounds__(256) void tot_pass(const int* __restrict__ blockHist,
                                                int* __restrict__ chunkStart) {
    int k = blockIdx.x * 256 + threadIdx.x;
    if (k >= NKB) return;
    int s = 0;
#pragma unroll 16
    for (int b = 0; b < PB; ++b) s += blockHist[(size_t)b * NKB + k];
    chunkStart[k] = s;
}

// exclusive scan of chunkStart[0..NKB) in place (single block, 512 threads)
__global__ __launch_bounds__(NKB) void scan_keys(int* __restrict__ chunkStart) {
    __shared__ int wsum[8];
    int t = threadIdx.x;
    int lane = t & 63, w = t >> 6;
    int v = chunkStart[t];
    int inc = v;
    for (int off = 1; off < 64; off <<= 1) {
        int nb = __shfl_up(inc, off, 64);
        if (lane >= off) inc += nb;
    }
    if (lane == 63) wsum[w] = inc;
    __syncthreads();
    if (t == 0) {
        int car = 0;
#pragma unroll
        for (int i = 0; i < 8; ++i) { int u = wsum[i]; wsum[i] = car; car += u; }
    }
    __syncthreads();
    chunkStart[t] = inc - v + wsum[w];
    if (t == 0) chunkStart[NKB] = NE;
}

__global__ __launch_bounds__(256) void offsets_pass(int* __restrict__ blockHist,
                                                    const int* __restrict__ chunkStart) {
    int k = blockIdx.x * 256 + threadIdx.x;
    if (k >= NKB) return;
    int r = chunkStart[k];
#pragma unroll 8
    for (int b = 0; b < PB; ++b) {
        size_t idx = (size_t)b * NKB + k;
        int v = blockHist[idx];
        blockHist[idx] = r;
        r += v;
    }
}

__global__ __launch_bounds__(PT) void scatter_pass(const int4* __restrict__ src4,
                                                   const int4* __restrict__ dst4,
                                                   const int* __restrict__ blockHist,
                                                   unsigned* __restrict__ pedge) {
    __shared__ int cur[NKB];  // 2 KB
    for (int k = threadIdx.x; k < NKB; k += PT)
        cur[k] = blockHist[(size_t)blockIdx.x * NKB + k];
    __syncthreads();
    const int NI8 = NE / 8;
    // same per-block traversal SET as hist_pass
    for (int j = blockIdx.x * PT + threadIdx.x; j < NI8; j += PB * PT) {
        int4 s0 = src4[2 * j];
        int4 s1 = src4[2 * j + 1];
        int4 d0 = dst4[2 * j];
        int4 d1 = dst4[2 * j + 1];
        int b0 = d0.x / BSZ, b1 = d0.y / BSZ, b2 = d0.z / BSZ, b3 = d0.w / BSZ;
        int b4 = d1.x / BSZ, b5 = d1.y / BSZ, b6 = d1.z / BSZ, b7 = d1.w / BSZ;
        int p0 = atomicAdd(&cur[b0], 1);
        int p1 = atomicAdd(&cur[b1], 1);
        int p2 = atomicAdd(&cur[b2], 1);
        int p3 = atomicAdd(&cur[b3], 1);
        int p4 = atomicAdd(&cur[b4], 1);
        int p5 = atomicAdd(&cur[b5], 1);
        int p6 = atomicAdd(&cur[b6], 1);
        int p7 = atomicAdd(&cur[b7], 1);
        pedge[p0] = ((unsigned)s0.x << LBITS) | (unsigned)(d0.x - b0 * BSZ);
        pedge[p1] = ((unsigned)s0.y << LBITS) | (unsigned)(d0.y - b1 * BSZ);
        pedge[p2] = ((unsigned)s0.z << LBITS) | (unsigned)(d0.z - b2 * BSZ);
        pedge[p3] = ((unsigned)s0.w << LBITS) | (unsigned)(d0.w - b3 * BSZ);
        pedge[p4] = ((unsigned)s1.x << LBITS) | (unsigned)(d1.x - b4 * BSZ);
        pedge[p5] = ((unsigned)s1.y << LBITS) | (unsigned)(d1.y - b5 * BSZ);
        pedge[p6] = ((unsigned)s1.z << LBITS) | (unsigned)(d1.z - b6 * BSZ);
        pedge[p7] = ((unsigned)s1.w << LBITS) | (unsigned)(d1.w - b7 * BSZ);
    }
}

// ---------------- stage 2: per-bucket sort by (slice, dst_local) -> CSR (one-time) ----------------
// Hybrid LDS edge cache: first ECAP edges of the segment live in LDS for pass 2.

__global__ __launch_bounds__(512) void subsort(const unsigned* __restrict__ pedge,
                                               const int* __restrict__ chunkStart,
                                               int* __restrict__ pedge2,
                                               int* __restrict__ rowStart,
                                               float* __restrict__ dis) {
    __shared__ int h[SKEYS];        // 8 KB: hist -> scan -> cur, in place
    __shared__ unsigned ebuf[ECAP]; // 36 KB edge cache
    __shared__ int wsum[8];
    int t = threadIdx.x;
    int b = blockIdx.x;
    int lane = t & 63, w = t >> 6;
    int e0 = chunkStart[b], e1 = chunkStart[b + 1];
    int n = e1 - e0;
    for (int k = t; k < SKEYS; k += 512) h[k] = 0;
    __syncthreads();
    for (int i = t; i < n; i += 512) {
        unsigned p = pedge[e0 + i];
        if (i < ECAP) ebuf[i] = p;
        int sv = (int)(p >> LBITS);
        atomicAdd(&h[(sv / SLICE_DIV) * 512 + (p & 511u)], 1);
    }
    __syncthreads();
    // degree (all slices of this local row) -> dis
    if (t < BSZ) {
        int dg = 1;  // self loop
#pragma unroll
        for (int s = 0; s < NCH; ++s) dg += h[s * 512 + t];
        int node = b * BSZ + t;
        if (node < NN) dis[node] = rsqrtf((float)dg);
    }
    // exclusive scan over 2048 bins in key order; thread t owns keys [4t, 4t+4)
    int vals[4];
    int s = 0;
#pragma unroll
    for (int j = 0; j < 4; ++j) { vals[j] = h[t * 4 + j]; s += vals[j]; }
    int inc = s;
    for (int off = 1; off < 64; off <<= 1) {
        int nb = __shfl_up(inc, off, 64);
        if (lane >= off) inc += nb;
    }
    if (lane == 63) wsum[w] = inc;
    __syncthreads();
    if (t == 0) {
        int car = 0;
#pragma unroll
        for (int i = 0; i < 8; ++i) { int u = wsum[i]; wsum[i] = car; car += u; }
    }
    __syncthreads();
    int run = inc - s + wsum[w];
#pragma unroll
    for (int j = 0; j < 4; ++j) {
        int k = t * 4 + j;
        h[k] = run;  // exclusive start within bucket (becomes cur)
        int dl = k & 511, sl = k >> 9;
        if (dl < BSZ)
            rowStart[(size_t)(b * NCH + sl) * BSZ + dl] = e0 + run;
        run += vals[j];
    }
    __syncthreads();
    for (int i = t; i < n; i += 512) {
        unsigned p = (i < ECAP) ? ebuf[i] : pedge[e0 + i];
        int sv = (int)(p >> LBITS);
        int key = (sv / SLICE_DIV) * 512 + (p & 511u);
        int pos = atomicAdd(&h[key], 1);
        pedge2[e0 + pos] = sv;
    }
    if (b == 0 && t == 0) rowStart[(size_t)NK * BSZ] = NE;
}

// ---------------- dense GEMMs, epilogue-scaled by dis[row] (xs' = (h@W)*dis) ----------------

#define GXT 512
#define GXR 128
__global__ __launch_bounds__(GXT) void gemm_x_w1(const float* __restrict__ x,
                                                 const float* __restrict__ W,
                                                 const float* __restrict__ dis,
                                                 float* __restrict__ out) {
    __shared__ float w[DIN * HID];  // 8 KB
    int t = threadIdx.x;
    for (int i = t; i < DIN * HID; i += GXT) w[i] = W[i];
    __syncthreads();
    int row = blockIdx.x * GXR + (t >> 2);
    int c0 = (t & 3) * 4;
    if (row >= NN) return;
    const float4* xr = reinterpret_cast<const float4*>(x + (size_t)row * DIN);
    float ax = 0.f, ay = 0.f, az = 0.f, aw = 0.f;
#pragma unroll
    for (int k4 = 0; k4 < DIN / 4; ++k4) {
        float4 xv = xr[k4];
        float4 w0 = *reinterpret_cast<const float4*>(&w[(4 * k4 + 0) * HID + c0]);
        float4 w1 = *reinterpret_cast<const float4*>(&w[(4 * k4 + 1) * HID + c0]);
        float4 w2 = *reinterpret_cast<const float4*>(&w[(4 * k4 + 2) * HID + c0]);
        float4 w3 = *reinterpret_cast<const float4*>(&w[(4 * k4 + 3) * HID + c0]);
        ax += xv.x * w0.x + xv.y * w1.x + xv.z * w2.x + xv.w * w3.x;
        ay += xv.x * w0.y + xv.y * w1.y + xv.z * w2.y + xv.w * w3.y;
        az += xv.x * w0.z + xv.y * w1.z + xv.z * w2.z + xv.w * w3.z;
        aw += xv.x * w0.w + xv.y * w1.w + xv.z * w2.w + xv.w * w3.w;
    }
    float dd = dis[row];
    *reinterpret_cast<float4*>(&out[(size_t)row * HID + c0]) =
        make_float4(ax * dd, ay * dd, az * dd, aw * dd);
}

__global__ __launch_bounds__(256) void gemm_h_w16(const float* __restrict__ h,
                                                  const float* __restrict__ W,
                                                  const float* __restrict__ dis,
                                                  float* __restrict__ out) {
    __shared__ float w[HID * HID];
    if (threadIdx.x < HID * HID) w[threadIdx.x] = W[threadIdx.x];
    __syncthreads();
    int row = blockIdx.x * 16 + (threadIdx.x >> 4);
    int c = threadIdx.x & 15;
    if (row >= NN) return;
    const float4* hr = reinterpret_cast<const float4*>(h + (size_t)row * HID);
    float acc = 0.f;
#pragma unroll
    for (int k4 = 0; k4 < HID / 4; ++k4) {
        float4 v = hr[k4];
        acc += v.x * w[(4 * k4 + 0) * HID + c] + v.y * w[(4 * k4 + 1) * HID + c]
             + v.z * w[(4 * k4 + 2) * HID + c] + v.w * w[(4 * k4 + 3) * HID + c];
    }
    out[row * HID + c] = acc * dis[row];
}

__global__ __launch_bounds__(256) void gemm_h_w2(const float* __restrict__ h,
                                                 const float* __restrict__ W,
                                                 const float* __restrict__ dis,
                                                 float* __restrict__ out) {
    int t = blockIdx.x * 256 + threadIdx.x;
    int row = t >> 1;
    int c = t & 1;
    if (row >= NN) return;
    const float* hr = h + (size_t)row * HID;
    float acc = 0.f;
#pragma unroll
    for (int k = 0; k < HID; ++k) acc += hr[k] * W[k * DOUT + c];
    out[row * DOUT + c] = acc * dis[row];
}

// ---------------- aggregation: fused per conv, slice-OUTER, interleaved dual-row streams ----------------

__device__ __forceinline__ void acc_edges(const int* __restrict__ pedge2,
                                          const float4* __restrict__ xs4,
                                          int e, int e1, int c4, float4& a) {
    for (; e + 3 < e1; e += 4) {  // 4 gathers in flight
        int s0 = pedge2[e], s1 = pedge2[e + 1];
        int s2 = pedge2[e + 2], s3 = pedge2[e + 3];
        float4 u0 = xs4[(s0 << 2) + c4];
        float4 u1 = xs4[(s1 << 2) + c4];
        float4 u2 = xs4[(s2 << 2) + c4];
        float4 u3 = xs4[(s3 << 2) + c4];
        a.x += (u0.x + u1.x) + (u2.x + u3.x);
        a.y += (u0.y + u1.y) + (u2.y + u3.y);
        a.z += (u0.z + u1.z) + (u2.z + u3.z);
        a.w += (u0.w + u1.w) + (u2.w + u3.w);
    }
    for (; e < e1; ++e) {
        float4 u = xs4[(pedge2[e] << 2) + c4];
        a.x += u.x; a.y += u.y; a.z += u.z; a.w += u.w;
    }
}

// both rows' fragments together: 8 loads in flight while both streams have >=4
__device__ __forceinline__ void acc2(const int* __restrict__ pedge2,
                                     const float4* __restrict__ xs4,
                                     int eA, int eAe, int eB, int eBe,
                                     int c4, float4& a0, float4& a1) {
    while (eA + 3 < eAe && eB + 3 < eBe) {
        int i0 = pedge2[eA], i1 = pedge2[eA + 1], i2 = pedge2[eA + 2], i3 = pedge2[eA + 3];
        int j0 = pedge2[eB], j1 = pedge2[eB + 1], j2 = pedge2[eB + 2], j3 = pedge2[eB + 3];
        float4 uA0 = xs4[(i0 << 2) + c4];
        float4 uA1 = xs4[(i1 << 2) + c4];
        float4 uA2 = xs4[(i2 << 2) + c4];
        float4 uA3 = xs4[(i3 << 2) + c4];
        float4 uB0 = xs4[(j0 << 2) + c4];
        float4 uB1 = xs4[(j1 << 2) + c4];
        float4 uB2 = xs4[(j2 << 2) + c4];
        float4 uB3 = xs4[(j3 << 2) + c4];
        a0.x += (uA0.x + uA1.x) + (uA2.x + uA3.x);
        a0.y += (uA0.y + uA1.y) + (uA2.y + uA3.y);
        a0.z += (uA0.z + uA1.z) + (uA2.z + uA3.z);
        a0.w += (uA0.w + uA1.w) + (uA2.w + uA3.w);
        a1.x += (uB0.x + uB1.x) + (uB2.x + uB3.x);
        a1.y += (uB0.y + uB1.y) + (uB2.y + uB3.y);
        a1.z += (uB0.z + uB1.z) + (uB2.z + uB3.z);
        a1.w += (uB0.w + uB1.w) + (uB2.w + uB3.w);
        eA += 4;
        eB += 4;
    }
    acc_edges(pedge2, xs4, eA, eAe, c4, a0);
    acc_edges(pedge2, xs4, eB, eBe, c4, a1);
}

__global__ __launch_bounds__(1024, 8) void agg16_all(const int* __restrict__ pedge2,
                                                     const int* __restrict__ rowStart,
                                                     const float* __restrict__ xs,
                                                     const float* __restrict__ dis,
                                                     const float* __restrict__ bias,
                                                     float* __restrict__ buf,
                                                     int relu) {
    int t = threadIdx.x;
    int b = blockIdx.x;
    int base = b * BSZ;
    int c4 = t & 3;
    int q = t >> 2;                         // quad 0..255
    int g0 = (q * BSZ) >> 8;                // balanced rows: 1 or 2 per quad
    int g1 = ((q + 1) * BSZ) >> 8;
    bool two = (g1 - g0) == 2;
    int n0 = base + g0, n1 = base + g0 + 1;
    bool v0 = n0 < NN;
    bool v1 = two && (n1 < NN);
    const float4* xs4 = reinterpret_cast<const float4*>(xs);
    float4* buf4 = reinterpret_cast<float4*>(buf);
    // prefetch ALL fragment bounds (12 independent loads, one latency)
    int sA[NCH], sB[NCH], sC[NCH];
#pragma unroll
    for (int r = 0; r < NCH; ++r) {
        const int* rs = rowStart + (size_t)(b * NCH + r) * BSZ + g0;
        sA[r] = v0 ? rs[0] : 0;
        sB[r] = v0 ? rs[1] : 0;
        sC[r] = v1 ? rs[2] : 0;
    }
    float4 a0 = make_float4(0.f, 0.f, 0.f, 0.f);
    float4 a1 = a0;
    if (v0) a0 = xs4[(n0 << 2) + c4];  // self-loop term
    if (v1) a1 = xs4[(n1 << 2) + c4];
    // slice-OUTER loop: all threads in all blocks touch src window r together
#pragma unroll
    for (int r = 0; r < NCH; ++r) {
        if (v1) acc2(pedge2, xs4, sA[r], sB[r], sB[r], sC[r], c4, a0, a1);
        else if (v0) acc_edges(pedge2, xs4, sA[r], sB[r], c4, a0);
    }
    float4 bb = reinterpret_cast<const float4*>(bias)[c4];
    if (v0) {
        float dd = dis[n0];
        float4 v = make_float4(dd * a0.x + bb.x, dd * a0.y + bb.y,
                               dd * a0.z + bb.z, dd * a0.w + bb.w);
        if (relu) { v.x = fmaxf(v.x, 0.f); v.y = fmaxf(v.y, 0.f);
                    v.z = fmaxf(v.z, 0.f); v.w = fmaxf(v.w, 0.f); }
        buf4[(n0 << 2) + c4] = v;
    }
    if (v1) {
        float dd = dis[n1];
        float4 v = make_float4(dd * a1.x + bb.x, dd * a1.y + bb.y,
                               dd * a1.z + bb.z, dd * a1.w + bb.w);
        if (relu) { v.x = fmaxf(v.x, 0.f); v.y = fmaxf(v.y, 0.f);
                    v.z = fmaxf(v.z, 0.f); v.w = fmaxf(v.w, 0.f); }
        buf4[(n1 << 2) + c4] = v;
    }
}

// conv2: one thread per dst row, float2 registers, fused bias + log_softmax.
__global__ __launch_bounds__(512) void agg2_lsm(const int* __restrict__ pedge2,
                                                const int* __restrict__ rowStart,
                                                const float* __restrict__ xs,
                                                const float* __restrict__ dis,
                                                const float* __restrict__ bias,
                                                float* __restrict__ out) {
    int t = threadIdx.x;
    int b = blockIdx.x;
    if (t >= BSZ) return;
    int node = b * BSZ + t;
    if (node >= NN) return;
    const float2* xs2 = reinterpret_cast<const float2*>(xs);
    float a0 = 0.f, a1 = 0.f;
#pragma unroll
    for (int s = 0; s < NCH; ++s) {
        const int* rs = rowStart + (size_t)(b * NCH + s) * BSZ;
        int e = rs[t], e1 = rs[t + 1];
        for (; e + 3 < e1; e += 4) {
            int s0 = pedge2[e], s1 = pedge2[e + 1];
            int s2 = pedge2[e + 2], s3 = pedge2[e + 3];
            float2 v0 = xs2[s0], v1 = xs2[s1], v2 = xs2[s2], v3 = xs2[s3];
            a0 += (v0.x + v1.x) + (v2.x + v3.x);
            a1 += (v0.y + v1.y) + (v2.y + v3.y);
        }
        for (; e < e1; ++e) {
            float2 v = xs2[pedge2[e]];
            a0 += v.x; a1 += v.y;
        }
    }
    float2 sv = xs2[node];
    float d = dis[node];
    float v0 = (a0 + sv.x) * d + bias[0];
    float v1 = (a1 + sv.y) * d + bias[1];
    float m = fmaxf(v0, v1);
    float lse = m + logf(__expf(v0 - m) + __expf(v1 - m));
    reinterpret_cast<float2*>(out)[node] = make_float2(v0 - lse, v1 - lse);
}

// ---------------- launch ----------------

extern "C" void kernel_launch(void* const* d_in, const int* in_sizes, int n_in,
                              void* d_out, int out_size, void* d_ws, size_t ws_size,
                              hipStream_t stream) {
    const float* x = (const float*)d_in[0];
    const int* ei = (const int*)d_in[1];
    const float* W1 = (const float*)d_in[2];
    const float* b1 = (const float*)d_in[3];
    const float* W3 = (const float*)d_in[4];
    const float* b3 = (const float*)d_in[5];
    const float* W2 = (const float*)d_in[6];
    const float* b2 = (const float*)d_in[7];
    float* out = (float*)d_out;

    const int4* src4 = (const int4*)ei;             // edge_index[0], 16B-aligned
    const int4* dst4 = (const int4*)(ei + NE);      // edge_index[1]

    // workspace layout (~58 MB). bufA aliases pedge (dead after subsort).
    int* W = (int*)d_ws;
    unsigned* pedge = (unsigned*)W;                        // NE
    int* pedge2 = W + NE;                                  // NE
    int* rowStart = W + 2 * (size_t)NE;                    // NK*BSZ + 4
    int* blockHist = rowStart + (size_t)NK * BSZ + 4;      // PB*NKB
    int* chunkStart = blockHist + (size_t)PB * NKB;        // NKB + 4
    float* dis = (float*)(chunkStart + NKB + 4);           // NN
    float* bufB = dis + NN;                                // NN*HID
    float* bufA = (float*)W;                               // aliases pedge

    const int B = 256;
    auto cdiv = [](long long a, long long b) { return (int)((a + b - 1) / b); };

    // partition: bucket sort -> per-bucket (slice,dst) sort -> CSR + dis
    hist_pass<<<PB, PT, 0, stream>>>(dst4, blockHist);
    tot_pass<<<cdiv(NKB, 256), 256, 0, stream>>>(blockHist, chunkStart);
    scan_keys<<<1, NKB, 0, stream>>>(chunkStart);
    offsets_pass<<<cdiv(NKB, 256), 256, 0, stream>>>(blockHist, chunkStart);
    scatter_pass<<<PB, PT, 0, stream>>>(src4, dst4, blockHist, pedge);
    subsort<<<NB, 512, 0, stream>>>(pedge, chunkStart, pedge2, rowStart, dis);

    // conv1: bufA = (x@W1)*dis ; fused slice-ordered aggregation into bufB
    gemm_x_w1<<<cdiv(NN, GXR), GXT, 0, stream>>>(x, W1, dis, bufA);
    agg16_all<<<NB, 1024, 0, stream>>>(pedge2, rowStart, bufA, dis, b1, bufB, 1);

    // conv3
    gemm_h_w16<<<cdiv(NN, 16), B, 0, stream>>>(bufB, W3, dis, bufA);
    agg16_all<<<NB, 1024, 0, stream>>>(pedge2, rowStart, bufA, dis, b3, bufB, 1);

    // conv2 + log_softmax
    gemm_h_w2<<<cdiv((long long)NN * DOUT, B), B, 0, stream>>>(bufB, W2, dis, bufA);
    agg2_lsm<<<NB, 512, 0, stream>>>(pedge2, rowStart, bufA, dis, b2, out);
}

// Round 22
// 276.292 us; speedup vs baseline: 1.1086x; 1.1086x over previous
//
#include <hip/hip_runtime.h>

#define NN 200000
#define NE 5000000
#define DIN 128
#define HID 16
#define DOUT 2
#define BSZ 391          // dst-buckets of 391 nodes: 512 buckets exactly
#define NB 512           // 2 blocks/CU on 256 CUs -> full occupancy, exact balance
#define LBITS 9          // local dst index bits (391 < 512)
#define NCH 4            // src slices of 50000 nodes (3.2 MB of xs' @ HID=16, fits L2)
#define SLICE_DIV 50000
#define NK (NB * NCH)    // 2048 (bucket,slice) segments for rowStart
#define NKB 512          // stage-1 sort keys = buckets only
#define SKEYS 2048       // subsort keys: (slice<<9)|dst_local
#define PB 512           // partition grid blocks (2/CU -> 16 waves)
#define PT 512           // partition block threads
#define ECAP 9216        // subsort LDS edge cache (mean segment 9766, 94% coverage)

static_assert((size_t)NB * BSZ >= NN, "bucket coverage");
static_assert((NN - 1) / SLICE_DIV == NCH - 1, "slice count");
static_assert(NE % 8 == 0, "int4-pair edge reads");

// ---------------- stage 1: counting sort by bucket = dst/391 (512 keys) ----------------

__global__ __launch_bounds__(PT) void hist_pass(const int4* __restrict__ dst4,
                                                int* __restrict__ blockHist) {
    __shared__ int h[NKB];  // 2 KB
    for (int k = threadIdx.x; k < NKB; k += PT) h[k] = 0;
    __syncthreads();
    const int NI8 = NE / 8;
    for (int j = blockIdx.x * PT + threadIdx.x; j < NI8; j += PB * PT) {
        int4 d0 = dst4[2 * j];
        int4 d1 = dst4[2 * j + 1];
        atomicAdd(&h[d0.x / BSZ], 1);
        atomicAdd(&h[d0.y / BSZ], 1);
        atomicAdd(&h[d0.z / BSZ], 1);
        atomicAdd(&h[d0.w / BSZ], 1);
        atomicAdd(&h[d1.x / BSZ], 1);
        atomicAdd(&h[d1.y / BSZ], 1);
        atomicAdd(&h[d1.z / BSZ], 1);
        atomicAdd(&h[d1.w / BSZ], 1);
    }
    __syncthreads();
    for (int k = threadIdx.x; k < NKB; k += PT)
        blockHist[(size_t)blockIdx.x * NKB + k] = h[k];
}

__global__ __launch_bounds__(256) void tot_pass(const int* __restrict__ blockHist,
                                                int* __restrict__ chunkStart) {
    int k = blockIdx.x * 256 + threadIdx.x;
    if (k >= NKB) return;
    int s = 0;
#pragma unroll 16
    for (int b = 0; b < PB; ++b) s += blockHist[(size_t)b * NKB + k];
    chunkStart[k] = s;
}

// exclusive scan of chunkStart[0..NKB) in place (single block, 512 threads)
__global__ __launch_bounds__(NKB) void scan_keys(int* __restrict__ chunkStart) {
    __shared__ int wsum[8];
    int t = threadIdx.x;
    int lane = t & 63, w = t >> 6;
    int v = chunkStart[t];
    int inc = v;
    for (int off = 1; off < 64; off <<= 1) {
        int nb = __shfl_up(inc, off, 64);
        if (lane >= off) inc += nb;
    }
    if (lane == 63) wsum[w] = inc;
    __syncthreads();
    if (t == 0) {
        int car = 0;
#pragma unroll
        for (int i = 0; i < 8; ++i) { int u = wsum[i]; wsum[i] = car; car += u; }
    }
    __syncthreads();
    chunkStart[t] = inc - v + wsum[w];
    if (t == 0) chunkStart[NKB] = NE;
}

__global__ __launch_bounds__(256) void offsets_pass(int* __restrict__ blockHist,
                                                    const int* __restrict__ chunkStart) {
    int k = blockIdx.x * 256 + threadIdx.x;
    if (k >= NKB) return;
    int r = chunkStart[k];
#pragma unroll 8
    for (int b = 0; b < PB; ++b) {
        size_t idx = (size_t)b * NKB + k;
        int v = blockHist[idx];
        blockHist[idx] = r;
        r += v;
    }
}

__global__ __launch_bounds__(PT) void scatter_pass(const int4* __restrict__ src4,
                                                   const int4* __restrict__ dst4,
                                                   const int* __restrict__ blockHist,
                                                   unsigned* __restrict__ pedge) {
    __shared__ int cur[NKB];  // 2 KB
    for (int k = threadIdx.x; k < NKB; k += PT)
        cur[k] = blockHist[(size_t)blockIdx.x * NKB + k];
    __syncthreads();
    const int NI8 = NE / 8;
    // same per-block traversal SET as hist_pass
    for (int j = blockIdx.x * PT + threadIdx.x; j < NI8; j += PB * PT) {
        int4 s0 = src4[2 * j];
        int4 s1 = src4[2 * j + 1];
        int4 d0 = dst4[2 * j];
        int4 d1 = dst4[2 * j + 1];
        int b0 = d0.x / BSZ, b1 = d0.y / BSZ, b2 = d0.z / BSZ, b3 = d0.w / BSZ;
        int b4 = d1.x / BSZ, b5 = d1.y / BSZ, b6 = d1.z / BSZ, b7 = d1.w / BSZ;
        int p0 = atomicAdd(&cur[b0], 1);
        int p1 = atomicAdd(&cur[b1], 1);
        int p2 = atomicAdd(&cur[b2], 1);
        int p3 = atomicAdd(&cur[b3], 1);
        int p4 = atomicAdd(&cur[b4], 1);
        int p5 = atomicAdd(&cur[b5], 1);
        int p6 = atomicAdd(&cur[b6], 1);
        int p7 = atomicAdd(&cur[b7], 1);
        pedge[p0] = ((unsigned)s0.x << LBITS) | (unsigned)(d0.x - b0 * BSZ);
        pedge[p1] = ((unsigned)s0.y << LBITS) | (unsigned)(d0.y - b1 * BSZ);
        pedge[p2] = ((unsigned)s0.z << LBITS) | (unsigned)(d0.z - b2 * BSZ);
        pedge[p3] = ((unsigned)s0.w << LBITS) | (unsigned)(d0.w - b3 * BSZ);
        pedge[p4] = ((unsigned)s1.x << LBITS) | (unsigned)(d1.x - b4 * BSZ);
        pedge[p5] = ((unsigned)s1.y << LBITS) | (unsigned)(d1.y - b5 * BSZ);
        pedge[p6] = ((unsigned)s1.z << LBITS) | (unsigned)(d1.z - b6 * BSZ);
        pedge[p7] = ((unsigned)s1.w << LBITS) | (unsigned)(d1.w - b7 * BSZ);
    }
}

// ---------------- stage 2: per-bucket sort by (slice, dst_local) -> CSR (one-time) ----------------

__global__ __launch_bounds__(512) void subsort(const unsigned* __restrict__ pedge,
                                               const int* __restrict__ chunkStart,
                                               int* __restrict__ pedge2,
                                               int* __restrict__ rowStart,
                                               float* __restrict__ dis) {
    __shared__ int h[SKEYS];        // 8 KB: hist -> scan -> cur, in place
    __shared__ unsigned ebuf[ECAP]; // 36 KB edge cache
    __shared__ int wsum[8];
    int t = threadIdx.x;
    int b = blockIdx.x;
    int lane = t & 63, w = t >> 6;
    int e0 = chunkStart[b], e1 = chunkStart[b + 1];
    int n = e1 - e0;
    for (int k = t; k < SKEYS; k += 512) h[k] = 0;
    __syncthreads();
    for (int i = t; i < n; i += 512) {
        unsigned p = pedge[e0 + i];
        if (i < ECAP) ebuf[i] = p;
        int sv = (int)(p >> LBITS);
        atomicAdd(&h[(sv / SLICE_DIV) * 512 + (p & 511u)], 1);
    }
    __syncthreads();
    // degree (all slices of this local row) -> dis
    if (t < BSZ) {
        int dg = 1;  // self loop
#pragma unroll
        for (int s = 0; s < NCH; ++s) dg += h[s * 512 + t];
        int node = b * BSZ + t;
        if (node < NN) dis[node] = rsqrtf((float)dg);
    }
    // exclusive scan over 2048 bins in key order; thread t owns keys [4t, 4t+4)
    int vals[4];
    int s = 0;
#pragma unroll
    for (int j = 0; j < 4; ++j) { vals[j] = h[t * 4 + j]; s += vals[j]; }
    int inc = s;
    for (int off = 1; off < 64; off <<= 1) {
        int nb = __shfl_up(inc, off, 64);
        if (lane >= off) inc += nb;
    }
    if (lane == 63) wsum[w] = inc;
    __syncthreads();
    if (t == 0) {
        int car = 0;
#pragma unroll
        for (int i = 0; i < 8; ++i) { int u = wsum[i]; wsum[i] = car; car += u; }
    }
    __syncthreads();
    int run = inc - s + wsum[w];
#pragma unroll
    for (int j = 0; j < 4; ++j) {
        int k = t * 4 + j;
        h[k] = run;  // exclusive start within bucket (becomes cur)
        int dl = k & 511, sl = k >> 9;
        if (dl < BSZ)
            rowStart[(size_t)(b * NCH + sl) * BSZ + dl] = e0 + run;
        run += vals[j];
    }
    __syncthreads();
    for (int i = t; i < n; i += 512) {
        unsigned p = (i < ECAP) ? ebuf[i] : pedge[e0 + i];
        int sv = (int)(p >> LBITS);
        int key = (sv / SLICE_DIV) * 512 + (p & 511u);
        int pos = atomicAdd(&h[key], 1);
        pedge2[e0 + pos] = sv;
    }
    if (b == 0 && t == 0) rowStart[(size_t)NK * BSZ] = NE;
}

// ---------------- dense GEMMs, epilogue-scaled by dis[row] (xs' = (h@W)*dis) ----------------

#define GXT 512
#define GXR 128
__global__ __launch_bounds__(GXT) void gemm_x_w1(const float* __restrict__ x,
                                                 const float* __restrict__ W,
                                                 const float* __restrict__ dis,
                                                 float* __restrict__ out) {
    __shared__ float w[DIN * HID];  // 8 KB
    int t = threadIdx.x;
    for (int i = t; i < DIN * HID; i += GXT) w[i] = W[i];
    __syncthreads();
    int row = blockIdx.x * GXR + (t >> 2);
    int c0 = (t & 3) * 4;
    if (row >= NN) return;
    const float4* xr = reinterpret_cast<const float4*>(x + (size_t)row * DIN);
    float ax = 0.f, ay = 0.f, az = 0.f, aw = 0.f;
#pragma unroll
    for (int k4 = 0; k4 < DIN / 4; ++k4) {
        float4 xv = xr[k4];
        float4 w0 = *reinterpret_cast<const float4*>(&w[(4 * k4 + 0) * HID + c0]);
        float4 w1 = *reinterpret_cast<const float4*>(&w[(4 * k4 + 1) * HID + c0]);
        float4 w2 = *reinterpret_cast<const float4*>(&w[(4 * k4 + 2) * HID + c0]);
        float4 w3 = *reinterpret_cast<const float4*>(&w[(4 * k4 + 3) * HID + c0]);
        ax += xv.x * w0.x + xv.y * w1.x + xv.z * w2.x + xv.w * w3.x;
        ay += xv.x * w0.y + xv.y * w1.y + xv.z * w2.y + xv.w * w3.y;
        az += xv.x * w0.z + xv.y * w1.z + xv.z * w2.z + xv.w * w3.z;
        aw += xv.x * w0.w + xv.y * w1.w + xv.z * w2.w + xv.w * w3.w;
    }
    float dd = dis[row];
    *reinterpret_cast<float4*>(&out[(size_t)row * HID + c0]) =
        make_float4(ax * dd, ay * dd, az * dd, aw * dd);
}

__global__ __launch_bounds__(256) void gemm_h_w16(const float* __restrict__ h,
                                                  const float* __restrict__ W,
                                                  const float* __restrict__ dis,
                                                  float* __restrict__ out) {
    __shared__ float w[HID * HID];
    if (threadIdx.x < HID * HID) w[threadIdx.x] = W[threadIdx.x];
    __syncthreads();
    int row = blockIdx.x * 16 + (threadIdx.x >> 4);
    int c = threadIdx.x & 15;
    if (row >= NN) return;
    const float4* hr = reinterpret_cast<const float4*>(h + (size_t)row * HID);
    float acc = 0.f;
#pragma unroll
    for (int k4 = 0; k4 < HID / 4; ++k4) {
        float4 v = hr[k4];
        acc += v.x * w[(4 * k4 + 0) * HID + c] + v.y * w[(4 * k4 + 1) * HID + c]
             + v.z * w[(4 * k4 + 2) * HID + c] + v.w * w[(4 * k4 + 3) * HID + c];
    }
    out[row * HID + c] = acc * dis[row];
}

__global__ __launch_bounds__(256) void gemm_h_w2(const float* __restrict__ h,
                                                 const float* __restrict__ W,
                                                 const float* __restrict__ dis,
                                                 float* __restrict__ out) {
    int t = blockIdx.x * 256 + threadIdx.x;
    int row = t >> 1;
    int c = t & 1;
    if (row >= NN) return;
    const float* hr = h + (size_t)row * HID;
    float acc = 0.f;
#pragma unroll
    for (int k = 0; k < HID; ++k) acc += hr[k] * W[k * DOUT + c];
    out[row * DOUT + c] = acc * dis[row];
}

// ---------------- aggregation: fused per conv, slice-OUTER, prefetched fragment bounds ----------------
// (R20 version: sequential per-row streams, VGPR ~20 — the acc2 interleave regressed)

__device__ __forceinline__ void acc_edges(const int* __restrict__ pedge2,
                                          const float4* __restrict__ xs4,
                                          int e, int e1, int c4, float4& a) {
    for (; e + 3 < e1; e += 4) {  // 4 gathers in flight
        int s0 = pedge2[e], s1 = pedge2[e + 1];
        int s2 = pedge2[e + 2], s3 = pedge2[e + 3];
        float4 u0 = xs4[(s0 << 2) + c4];
        float4 u1 = xs4[(s1 << 2) + c4];
        float4 u2 = xs4[(s2 << 2) + c4];
        float4 u3 = xs4[(s3 << 2) + c4];
        a.x += (u0.x + u1.x) + (u2.x + u3.x);
        a.y += (u0.y + u1.y) + (u2.y + u3.y);
        a.z += (u0.z + u1.z) + (u2.z + u3.z);
        a.w += (u0.w + u1.w) + (u2.w + u3.w);
    }
    for (; e < e1; ++e) {
        float4 u = xs4[(pedge2[e] << 2) + c4];
        a.x += u.x; a.y += u.y; a.z += u.z; a.w += u.w;
    }
}

__global__ __launch_bounds__(1024, 8) void agg16_all(const int* __restrict__ pedge2,
                                                     const int* __restrict__ rowStart,
                                                     const float* __restrict__ xs,
                                                     const float* __restrict__ dis,
                                                     const float* __restrict__ bias,
                                                     float* __restrict__ buf,
                                                     int relu) {
    int t = threadIdx.x;
    int b = blockIdx.x;
    int base = b * BSZ;
    int c4 = t & 3;
    int q = t >> 2;                         // quad 0..255
    int g0 = (q * BSZ) >> 8;                // balanced rows: 1 or 2 per quad
    int g1 = ((q + 1) * BSZ) >> 8;
    bool two = (g1 - g0) == 2;
    int n0 = base + g0, n1 = base + g0 + 1;
    bool v0 = n0 < NN;
    bool v1 = two && (n1 < NN);
    const float4* xs4 = reinterpret_cast<const float4*>(xs);
    float4* buf4 = reinterpret_cast<float4*>(buf);
    // prefetch ALL fragment bounds (12 independent loads, one latency)
    int sA[NCH], sB[NCH], sC[NCH];
#pragma unroll
    for (int r = 0; r < NCH; ++r) {
        const int* rs = rowStart + (size_t)(b * NCH + r) * BSZ + g0;
        sA[r] = v0 ? rs[0] : 0;
        sB[r] = v0 ? rs[1] : 0;
        sC[r] = v1 ? rs[2] : 0;
    }
    float4 a0 = make_float4(0.f, 0.f, 0.f, 0.f);
    float4 a1 = a0;
    if (v0) a0 = xs4[(n0 << 2) + c4];  // self-loop term
    if (v1) a1 = xs4[(n1 << 2) + c4];
    // slice-OUTER loop: all threads in all blocks touch src window r together
#pragma unroll
    for (int r = 0; r < NCH; ++r) {
        if (v0) acc_edges(pedge2, xs4, sA[r], sB[r], c4, a0);
        if (v1) acc_edges(pedge2, xs4, sB[r], sC[r], c4, a1);
    }
    float4 bb = reinterpret_cast<const float4*>(bias)[c4];
    if (v0) {
        float dd = dis[n0];
        float4 v = make_float4(dd * a0.x + bb.x, dd * a0.y + bb.y,
                               dd * a0.z + bb.z, dd * a0.w + bb.w);
        if (relu) { v.x = fmaxf(v.x, 0.f); v.y = fmaxf(v.y, 0.f);
                    v.z = fmaxf(v.z, 0.f); v.w = fmaxf(v.w, 0.f); }
        buf4[(n0 << 2) + c4] = v;
    }
    if (v1) {
        float dd = dis[n1];
        float4 v = make_float4(dd * a1.x + bb.x, dd * a1.y + bb.y,
                               dd * a1.z + bb.z, dd * a1.w + bb.w);
        if (relu) { v.x = fmaxf(v.x, 0.f); v.y = fmaxf(v.y, 0.f);
                    v.z = fmaxf(v.z, 0.f); v.w = fmaxf(v.w, 0.f); }
        buf4[(n1 << 2) + c4] = v;
    }
}

// conv2: one thread per dst row, float2 registers, fused bias + log_softmax.
__global__ __launch_bounds__(512) void agg2_lsm(const int* __restrict__ pedge2,
                                                const int* __restrict__ rowStart,
                                                const float* __restrict__ xs,
                                                const float* __restrict__ dis,
                                                const float* __restrict__ bias,
                                                float* __restrict__ out) {
    int t = threadIdx.x;
    int b = blockIdx.x;
    if (t >= BSZ) return;
    int node = b * BSZ + t;
    if (node >= NN) return;
    const float2* xs2 = reinterpret_cast<const float2*>(xs);
    float a0 = 0.f, a1 = 0.f;
#pragma unroll
    for (int s = 0; s < NCH; ++s) {
        const int* rs = rowStart + (size_t)(b * NCH + s) * BSZ;
        int e = rs[t], e1 = rs[t + 1];
        for (; e + 3 < e1; e += 4) {
            int s0 = pedge2[e], s1 = pedge2[e + 1];
            int s2 = pedge2[e + 2], s3 = pedge2[e + 3];
            float2 v0 = xs2[s0], v1 = xs2[s1], v2 = xs2[s2], v3 = xs2[s3];
            a0 += (v0.x + v1.x) + (v2.x + v3.x);
            a1 += (v0.y + v1.y) + (v2.y + v3.y);
        }
        for (; e < e1; ++e) {
            float2 v = xs2[pedge2[e]];
            a0 += v.x; a1 += v.y;
        }
    }
    float2 sv = xs2[node];
    float d = dis[node];
    float v0 = (a0 + sv.x) * d + bias[0];
    float v1 = (a1 + sv.y) * d + bias[1];
    float m = fmaxf(v0, v1);
    float lse = m + logf(__expf(v0 - m) + __expf(v1 - m));
    reinterpret_cast<float2*>(out)[node] = make_float2(v0 - lse, v1 - lse);
}

// ---------------- launch ----------------

extern "C" void kernel_launch(void* const* d_in, const int* in_sizes, int n_in,
                              void* d_out, int out_size, void* d_ws, size_t ws_size,
                              hipStream_t stream) {
    const float* x = (const float*)d_in[0];
    const int* ei = (const int*)d_in[1];
    const float* W1 = (const float*)d_in[2];
    const float* b1 = (const float*)d_in[3];
    const float* W3 = (const float*)d_in[4];
    const float* b3 = (const float*)d_in[5];
    const float* W2 = (const float*)d_in[6];
    const float* b2 = (const float*)d_in[7];
    float* out = (float*)d_out;

    const int4* src4 = (const int4*)ei;             // edge_index[0], 16B-aligned
    const int4* dst4 = (const int4*)(ei + NE);      // edge_index[1]

    // workspace layout (~58 MB). bufA aliases pedge (dead after subsort).
    int* W = (int*)d_ws;
    unsigned* pedge = (unsigned*)W;                        // NE
    int* pedge2 = W + NE;                                  // NE
    int* rowStart = W + 2 * (size_t)NE;                    // NK*BSZ + 4
    int* blockHist = rowStart + (size_t)NK * BSZ + 4;      // PB*NKB
    int* chunkStart = blockHist + (size_t)PB * NKB;        // NKB + 4
    float* dis = (float*)(chunkStart + NKB + 4);           // NN
    float* bufB = dis + NN;                                // NN*HID
    float* bufA = (float*)W;                               // aliases pedge

    const int B = 256;
    auto cdiv = [](long long a, long long b) { return (int)((a + b - 1) / b); };

    // partition: bucket sort -> per-bucket (slice,dst) sort -> CSR + dis
    hist_pass<<<PB, PT, 0, stream>>>(dst4, blockHist);
    tot_pass<<<cdiv(NKB, 256), 256, 0, stream>>>(blockHist, chunkStart);
    scan_keys<<<1, NKB, 0, stream>>>(chunkStart);
    offsets_pass<<<cdiv(NKB, 256), 256, 0, stream>>>(blockHist, chunkStart);
    scatter_pass<<<PB, PT, 0, stream>>>(src4, dst4, blockHist, pedge);
    subsort<<<NB, 512, 0, stream>>>(pedge, chunkStart, pedge2, rowStart, dis);

    // conv1: bufA = (x@W1)*dis ; fused slice-ordered aggregation into bufB
    gemm_x_w1<<<cdiv(NN, GXR), GXT, 0, stream>>>(x, W1, dis, bufA);
    agg16_all<<<NB, 1024, 0, stream>>>(pedge2, rowStart, bufA, dis, b1, bufB, 1);

    // conv3
    gemm_h_w16<<<cdiv(NN, 16), B, 0, stream>>>(bufB, W3, dis, bufA);
    agg16_all<<<NB, 1024, 0, stream>>>(pedge2, rowStart, bufA, dis, b3, bufB, 1);

    // conv2 + log_softmax
    gemm_h_w2<<<cdiv((long long)NN * DOUT, B), B, 0, stream>>>(bufB, W2, dis, bufA);
    agg2_lsm<<<NB, 512, 0, stream>>>(pedge2, rowStart, bufA, dis, b2, out);
}

// Round 23
// 264.399 us; speedup vs baseline: 1.1585x; 1.0450x over previous
//
#include <hip/hip_runtime.h>

#define NN 200000
#define NE 5000000
#define DIN 128
#define HID 16
#define DOUT 2
#define BSZ 391          // dst-buckets of 391 nodes: 512 buckets exactly
#define NB 512           // 2 blocks/CU on 256 CUs -> full occupancy, exact balance
#define LBITS 9          // local dst index bits (391 < 512)
#define NCH 4            // src slices of 50000 nodes (3.2 MB of xs' @ HID=16, fits L2)
#define SLICE_DIV 50000
#define NK (NB * NCH)    // 2048 (bucket,slice) segments for rowStart
#define NKB 512          // stage-1 sort keys = buckets only
#define SKEYS 2048       // subsort keys: (slice<<9)|dst_local
#define PB 512           // partition grid blocks (2/CU -> 16 waves)
#define PT 512           // partition block threads
#define ECAP 9216        // subsort LDS edge cache (mean segment 9766, 94% coverage)

static_assert((size_t)NB * BSZ >= NN, "bucket coverage");
static_assert((NN - 1) / SLICE_DIV == NCH - 1, "slice count");
static_assert(NE % 8 == 0, "int4-pair edge reads");

// ---------------- stage 1: counting sort by bucket = dst/391 (512 keys) ----------------

__global__ __launch_bounds__(PT) void hist_pass(const int4* __restrict__ dst4,
                                                int* __restrict__ blockHist) {
    __shared__ int h[NKB];  // 2 KB
    for (int k = threadIdx.x; k < NKB; k += PT) h[k] = 0;
    __syncthreads();
    const int NI8 = NE / 8;
    for (int j = blockIdx.x * PT + threadIdx.x; j < NI8; j += PB * PT) {
        int4 d0 = dst4[2 * j];
        int4 d1 = dst4[2 * j + 1];
        atomicAdd(&h[d0.x / BSZ], 1);
        atomicAdd(&h[d0.y / BSZ], 1);
        atomicAdd(&h[d0.z / BSZ], 1);
        atomicAdd(&h[d0.w / BSZ], 1);
        atomicAdd(&h[d1.x / BSZ], 1);
        atomicAdd(&h[d1.y / BSZ], 1);
        atomicAdd(&h[d1.z / BSZ], 1);
        atomicAdd(&h[d1.w / BSZ], 1);
    }
    __syncthreads();
    for (int k = threadIdx.x; k < NKB; k += PT)
        blockHist[(size_t)blockIdx.x * NKB + k] = h[k];
}

__global__ __launch_bounds__(256) void tot_pass(const int* __restrict__ blockHist,
                                                int* __restrict__ chunkStart) {
    int k = blockIdx.x * 256 + threadIdx.x;
    if (k >= NKB) return;
    int s = 0;
#pragma unroll 16
    for (int b = 0; b < PB; ++b) s += blockHist[(size_t)b * NKB + k];
    chunkStart[k] = s;
}

// exclusive scan of chunkStart[0..NKB) in place (single block, 512 threads)
__global__ __launch_bounds__(NKB) void scan_keys(int* __restrict__ chunkStart) {
    __shared__ int wsum[8];
    int t = threadIdx.x;
    int lane = t & 63, w = t >> 6;
    int v = chunkStart[t];
    int inc = v;
    for (int off = 1; off < 64; off <<= 1) {
        int nb = __shfl_up(inc, off, 64);
        if (lane >= off) inc += nb;
    }
    if (lane == 63) wsum[w] = inc;
    __syncthreads();
    if (t == 0) {
        int car = 0;
#pragma unroll
        for (int i = 0; i < 8; ++i) { int u = wsum[i]; wsum[i] = car; car += u; }
    }
    __syncthreads();
    chunkStart[t] = inc - v + wsum[w];
    if (t == 0) chunkStart[NKB] = NE;
}

__global__ __launch_bounds__(256) void offsets_pass(int* __restrict__ blockHist,
                                                    const int* __restrict__ chunkStart) {
    int k = blockIdx.x * 256 + threadIdx.x;
    if (k >= NKB) return;
    int r = chunkStart[k];
#pragma unroll 8
    for (int b = 0; b < PB; ++b) {
        size_t idx = (size_t)b * NKB + k;
        int v = blockHist[idx];
        blockHist[idx] = r;
        r += v;
    }
}

__global__ __launch_bounds__(PT) void scatter_pass(const int4* __restrict__ src4,
                                                   const int4* __restrict__ dst4,
                                                   const int* __restrict__ blockHist,
                                                   unsigned* __restrict__ pedge) {
    __shared__ int cur[NKB];  // 2 KB
    for (int k = threadIdx.x; k < NKB; k += PT)
        cur[k] = blockHist[(size_t)blockIdx.x * NKB + k];
    __syncthreads();
    const int NI8 = NE / 8;
    // same per-block traversal SET as hist_pass
    for (int j = blockIdx.x * PT + threadIdx.x; j < NI8; j += PB * PT) {
        int4 s0 = src4[2 * j];
        int4 s1 = src4[2 * j + 1];
        int4 d0 = dst4[2 * j];
        int4 d1 = dst4[2 * j + 1];
        int b0 = d0.x / BSZ, b1 = d0.y / BSZ, b2 = d0.z / BSZ, b3 = d0.w / BSZ;
        int b4 = d1.x / BSZ, b5 = d1.y / BSZ, b6 = d1.z / BSZ, b7 = d1.w / BSZ;
        int p0 = atomicAdd(&cur[b0], 1);
        int p1 = atomicAdd(&cur[b1], 1);
        int p2 = atomicAdd(&cur[b2], 1);
        int p3 = atomicAdd(&cur[b3], 1);
        int p4 = atomicAdd(&cur[b4], 1);
        int p5 = atomicAdd(&cur[b5], 1);
        int p6 = atomicAdd(&cur[b6], 1);
        int p7 = atomicAdd(&cur[b7], 1);
        pedge[p0] = ((unsigned)s0.x << LBITS) | (unsigned)(d0.x - b0 * BSZ);
        pedge[p1] = ((unsigned)s0.y << LBITS) | (unsigned)(d0.y - b1 * BSZ);
        pedge[p2] = ((unsigned)s0.z << LBITS) | (unsigned)(d0.z - b2 * BSZ);
        pedge[p3] = ((unsigned)s0.w << LBITS) | (unsigned)(d0.w - b3 * BSZ);
        pedge[p4] = ((unsigned)s1.x << LBITS) | (unsigned)(d1.x - b4 * BSZ);
        pedge[p5] = ((unsigned)s1.y << LBITS) | (unsigned)(d1.y - b5 * BSZ);
        pedge[p6] = ((unsigned)s1.z << LBITS) | (unsigned)(d1.z - b6 * BSZ);
        pedge[p7] = ((unsigned)s1.w << LBITS) | (unsigned)(d1.w - b7 * BSZ);
    }
}

// ---------------- stage 2: per-bucket sort by (slice, dst_local) -> CSR (one-time) ----------------

__global__ __launch_bounds__(512) void subsort(const unsigned* __restrict__ pedge,
                                               const int* __restrict__ chunkStart,
                                               int* __restrict__ pedge2,
                                               int* __restrict__ rowStart,
                                               float* __restrict__ dis) {
    __shared__ int h[SKEYS];        // 8 KB: hist -> scan -> cur, in place
    __shared__ unsigned ebuf[ECAP]; // 36 KB edge cache
    __shared__ int wsum[8];
    int t = threadIdx.x;
    int b = blockIdx.x;
    int lane = t & 63, w = t >> 6;
    int e0 = chunkStart[b], e1 = chunkStart[b + 1];
    int n = e1 - e0;
    for (int k = t; k < SKEYS; k += 512) h[k] = 0;
    __syncthreads();
    for (int i = t; i < n; i += 512) {
        unsigned p = pedge[e0 + i];
        if (i < ECAP) ebuf[i] = p;
        int sv = (int)(p >> LBITS);
        atomicAdd(&h[(sv / SLICE_DIV) * 512 + (p & 511u)], 1);
    }
    __syncthreads();
    // degree (all slices of this local row) -> dis
    if (t < BSZ) {
        int dg = 1;  // self loop
#pragma unroll
        for (int s = 0; s < NCH; ++s) dg += h[s * 512 + t];
        int node = b * BSZ + t;
        if (node < NN) dis[node] = rsqrtf((float)dg);
    }
    // exclusive scan over 2048 bins in key order; thread t owns keys [4t, 4t+4)
    int vals[4];
    int s = 0;
#pragma unroll
    for (int j = 0; j < 4; ++j) { vals[j] = h[t * 4 + j]; s += vals[j]; }
    int inc = s;
    for (int off = 1; off < 64; off <<= 1) {
        int nb = __shfl_up(inc, off, 64);
        if (lane >= off) inc += nb;
    }
    if (lane == 63) wsum[w] = inc;
    __syncthreads();
    if (t == 0) {
        int car = 0;
#pragma unroll
        for (int i = 0; i < 8; ++i) { int u = wsum[i]; wsum[i] = car; car += u; }
    }
    __syncthreads();
    int run = inc - s + wsum[w];
#pragma unroll
    for (int j = 0; j < 4; ++j) {
        int k = t * 4 + j;
        h[k] = run;  // exclusive start within bucket (becomes cur)
        int dl = k & 511, sl = k >> 9;
        if (dl < BSZ)
            rowStart[(size_t)(b * NCH + sl) * BSZ + dl] = e0 + run;
        run += vals[j];
    }
    __syncthreads();
    for (int i = t; i < n; i += 512) {
        unsigned p = (i < ECAP) ? ebuf[i] : pedge[e0 + i];
        int sv = (int)(p >> LBITS);
        int key = (sv / SLICE_DIV) * 512 + (p & 511u);
        int pos = atomicAdd(&h[key], 1);
        pedge2[e0 + pos] = sv;
    }
    if (b == 0 && t == 0) rowStart[(size_t)NK * BSZ] = NE;
}

// ---------------- conv1 GEMM: bufA = (x @ W1) * dis ----------------

#define GXT 512
#define GXR 128
__global__ __launch_bounds__(GXT) void gemm_x_w1(const float* __restrict__ x,
                                                 const float* __restrict__ W,
                                                 const float* __restrict__ dis,
                                                 float* __restrict__ out) {
    __shared__ float w[DIN * HID];  // 8 KB
    int t = threadIdx.x;
    for (int i = t; i < DIN * HID; i += GXT) w[i] = W[i];
    __syncthreads();
    int row = blockIdx.x * GXR + (t >> 2);
    int c0 = (t & 3) * 4;
    if (row >= NN) return;
    const float4* xr = reinterpret_cast<const float4*>(x + (size_t)row * DIN);
    float ax = 0.f, ay = 0.f, az = 0.f, aw = 0.f;
#pragma unroll
    for (int k4 = 0; k4 < DIN / 4; ++k4) {
        float4 xv = xr[k4];
        float4 w0 = *reinterpret_cast<const float4*>(&w[(4 * k4 + 0) * HID + c0]);
        float4 w1 = *reinterpret_cast<const float4*>(&w[(4 * k4 + 1) * HID + c0]);
        float4 w2 = *reinterpret_cast<const float4*>(&w[(4 * k4 + 2) * HID + c0]);
        float4 w3 = *reinterpret_cast<const float4*>(&w[(4 * k4 + 3) * HID + c0]);
        ax += xv.x * w0.x + xv.y * w1.x + xv.z * w2.x + xv.w * w3.x;
        ay += xv.x * w0.y + xv.y * w1.y + xv.z * w2.y + xv.w * w3.y;
        az += xv.x * w0.z + xv.y * w1.z + xv.z * w2.z + xv.w * w3.z;
        aw += xv.x * w0.w + xv.y * w1.w + xv.z * w2.w + xv.w * w3.w;
    }
    float dd = dis[row];
    *reinterpret_cast<float4*>(&out[(size_t)row * HID + c0]) =
        make_float4(ax * dd, ay * dd, az * dd, aw * dd);
}

// ---------------- aggregation fused with next-layer GEMM (quad-shuffle) ----------------
// mode 0: out_row16 = (relu(dis*sum + bias) @ Wn[16x16]) * dis   (conv1 -> conv3 input)
// mode 1: out_row2  = (relu(dis*sum + bias) @ Wn[16x2])  * dis   (conv3 -> conv2 input)

__device__ __forceinline__ void acc_edges(const int* __restrict__ pedge2,
                                          const float4* __restrict__ xs4,
                                          int e, int e1, int c4, float4& a) {
    for (; e + 3 < e1; e += 4) {  // 4 gathers in flight
        int s0 = pedge2[e], s1 = pedge2[e + 1];
        int s2 = pedge2[e + 2], s3 = pedge2[e + 3];
        float4 u0 = xs4[(s0 << 2) + c4];
        float4 u1 = xs4[(s1 << 2) + c4];
        float4 u2 = xs4[(s2 << 2) + c4];
        float4 u3 = xs4[(s3 << 2) + c4];
        a.x += (u0.x + u1.x) + (u2.x + u3.x);
        a.y += (u0.y + u1.y) + (u2.y + u3.y);
        a.z += (u0.z + u1.z) + (u2.z + u3.z);
        a.w += (u0.w + u1.w) + (u2.w + u3.w);
    }
    for (; e < e1; ++e) {
        float4 u = xs4[(pedge2[e] << 2) + c4];
        a.x += u.x; a.y += u.y; a.z += u.z; a.w += u.w;
    }
}

// epilogue: h = relu(dis*a + bias); then h @ Wn via quad shuffles; write *dis.
__device__ __forceinline__ void epi_store(const float* __restrict__ wl,
                                          float* __restrict__ buf,
                                          int node, int c4, const float4& a,
                                          const float4& bb, float dd, int mode) {
    float4 h;
    h.x = fmaxf(dd * a.x + bb.x, 0.f);
    h.y = fmaxf(dd * a.y + bb.y, 0.f);
    h.z = fmaxf(dd * a.z + bb.z, 0.f);
    h.w = fmaxf(dd * a.w + bb.w, 0.f);
    if (mode == 0) {
        // y[c0..c0+3] = sum_k h[k] * W[k][c0..c0+3], W row-major 16x16 in LDS
        float4 y = make_float4(0.f, 0.f, 0.f, 0.f);
        int c0 = c4 * 4;
#pragma unroll
        for (int l = 0; l < 4; ++l) {
            float h0 = __shfl(h.x, l, 4);
            float h1 = __shfl(h.y, l, 4);
            float h2 = __shfl(h.z, l, 4);
            float h3 = __shfl(h.w, l, 4);
            const float* wr = wl + (4 * l) * HID + c0;
            float4 w0 = *reinterpret_cast<const float4*>(wr);
            float4 w1 = *reinterpret_cast<const float4*>(wr + HID);
            float4 w2 = *reinterpret_cast<const float4*>(wr + 2 * HID);
            float4 w3 = *reinterpret_cast<const float4*>(wr + 3 * HID);
            y.x += h0 * w0.x + h1 * w1.x + h2 * w2.x + h3 * w3.x;
            y.y += h0 * w0.y + h1 * w1.y + h2 * w2.y + h3 * w3.y;
            y.z += h0 * w0.z + h1 * w1.z + h2 * w2.z + h3 * w3.z;
            y.w += h0 * w0.w + h1 * w1.w + h2 * w2.w + h3 * w3.w;
        }
        reinterpret_cast<float4*>(buf)[(node << 2) + c4] =
            make_float4(y.x * dd, y.y * dd, y.z * dd, y.w * dd);
    } else {
        // z[c] = sum_k h[k] * W2[k*2+c]; lane l owns k = 4l..4l+3; butterfly sum
        const float* wr = wl + (4 * c4) * DOUT;
        float p0 = h.x * wr[0] + h.y * wr[2] + h.z * wr[4] + h.w * wr[6];
        float p1 = h.x * wr[1] + h.y * wr[3] + h.z * wr[5] + h.w * wr[7];
        p0 += __shfl_xor(p0, 1, 4);
        p0 += __shfl_xor(p0, 2, 4);
        p1 += __shfl_xor(p1, 1, 4);
        p1 += __shfl_xor(p1, 2, 4);
        if (c4 == 0)
            reinterpret_cast<float2*>(buf)[node] = make_float2(p0 * dd, p1 * dd);
    }
}

__global__ __launch_bounds__(1024, 8) void agg16_all(const int* __restrict__ pedge2,
                                                     const int* __restrict__ rowStart,
                                                     const float* __restrict__ xs,
                                                     const float* __restrict__ dis,
                                                     const float* __restrict__ bias,
                                                     const float* __restrict__ Wn,
                                                     float* __restrict__ buf,
                                                     int mode) {
    __shared__ float wl[HID * HID];  // 1 KB (mode 0) / 128 B used (mode 1)
    int t = threadIdx.x;
    int nw = (mode == 0) ? HID * HID : HID * DOUT;
    if (t < nw) wl[t] = Wn[t];
    __syncthreads();
    int b = blockIdx.x;
    int base = b * BSZ;
    int c4 = t & 3;
    int q = t >> 2;                         // quad 0..255
    int g0 = (q * BSZ) >> 8;                // balanced rows: 1 or 2 per quad
    int g1 = ((q + 1) * BSZ) >> 8;
    bool two = (g1 - g0) == 2;
    int n0 = base + g0, n1 = base + g0 + 1;
    bool v0 = n0 < NN;
    bool v1 = two && (n1 < NN);
    const float4* xs4 = reinterpret_cast<const float4*>(xs);
    // prefetch ALL fragment bounds (12 independent loads, one latency)
    int sA[NCH], sB[NCH], sC[NCH];
#pragma unroll
    for (int r = 0; r < NCH; ++r) {
        const int* rs = rowStart + (size_t)(b * NCH + r) * BSZ + g0;
        sA[r] = v0 ? rs[0] : 0;
        sB[r] = v0 ? rs[1] : 0;
        sC[r] = v1 ? rs[2] : 0;
    }
    float4 a0 = make_float4(0.f, 0.f, 0.f, 0.f);
    float4 a1 = a0;
    if (v0) a0 = xs4[(n0 << 2) + c4];  // self-loop term
    if (v1) a1 = xs4[(n1 << 2) + c4];
    // slice-OUTER loop: all threads in all blocks touch src window r together
#pragma unroll
    for (int r = 0; r < NCH; ++r) {
        if (v0) acc_edges(pedge2, xs4, sA[r], sB[r], c4, a0);
        if (v1) acc_edges(pedge2, xs4, sB[r], sC[r], c4, a1);
    }
    float4 bb = reinterpret_cast<const float4*>(bias)[c4];
    if (v0) epi_store(wl, buf, n0, c4, a0, bb, dis[n0], mode);
    if (v1) epi_store(wl, buf, n1, c4, a1, bb, dis[n1], mode);
}

// conv2: one thread per dst row, float2 registers, fused bias + log_softmax.
__global__ __launch_bounds__(512) void agg2_lsm(const int* __restrict__ pedge2,
                                                const int* __restrict__ rowStart,
                                                const float* __restrict__ xs,
                                                const float* __restrict__ dis,
                                                const float* __restrict__ bias,
                                                float* __restrict__ out) {
    int t = threadIdx.x;
    int b = blockIdx.x;
    if (t >= BSZ) return;
    int node = b * BSZ + t;
    if (node >= NN) return;
    const float2* xs2 = reinterpret_cast<const float2*>(xs);
    float a0 = 0.f, a1 = 0.f;
#pragma unroll
    for (int s = 0; s < NCH; ++s) {
        const int* rs = rowStart + (size_t)(b * NCH + s) * BSZ;
        int e = rs[t], e1 = rs[t + 1];
        for (; e + 3 < e1; e += 4) {
            int s0 = pedge2[e], s1 = pedge2[e + 1];
            int s2 = pedge2[e + 2], s3 = pedge2[e + 3];
            float2 v0 = xs2[s0], v1 = xs2[s1], v2 = xs2[s2], v3 = xs2[s3];
            a0 += (v0.x + v1.x) + (v2.x + v3.x);
            a1 += (v0.y + v1.y) + (v2.y + v3.y);
        }
        for (; e < e1; ++e) {
            float2 v = xs2[pedge2[e]];
            a0 += v.x; a1 += v.y;
        }
    }
    float2 sv = xs2[node];
    float d = dis[node];
    float v0 = (a0 + sv.x) * d + bias[0];
    float v1 = (a1 + sv.y) * d + bias[1];
    float m = fmaxf(v0, v1);
    float lse = m + logf(__expf(v0 - m) + __expf(v1 - m));
    reinterpret_cast<float2*>(out)[node] = make_float2(v0 - lse, v1 - lse);
}

// ---------------- launch ----------------

extern "C" void kernel_launch(void* const* d_in, const int* in_sizes, int n_in,
                              void* d_out, int out_size, void* d_ws, size_t ws_size,
                              hipStream_t stream) {
    const float* x = (const float*)d_in[0];
    const int* ei = (const int*)d_in[1];
    const float* W1 = (const float*)d_in[2];
    const float* b1 = (const float*)d_in[3];
    const float* W3 = (const float*)d_in[4];
    const float* b3 = (const float*)d_in[5];
    const float* W2 = (const float*)d_in[6];
    const float* b2 = (const float*)d_in[7];
    float* out = (float*)d_out;

    const int4* src4 = (const int4*)ei;             // edge_index[0], 16B-aligned
    const int4* dst4 = (const int4*)(ei + NE);      // edge_index[1]

    // workspace layout (~58 MB). bufA aliases pedge (dead after subsort).
    int* W = (int*)d_ws;
    unsigned* pedge = (unsigned*)W;                        // NE
    int* pedge2 = W + NE;                                  // NE
    int* rowStart = W + 2 * (size_t)NE;                    // NK*BSZ + 4
    int* blockHist = rowStart + (size_t)NK * BSZ + 4;      // PB*NKB
    int* chunkStart = blockHist + (size_t)PB * NKB;        // NKB + 4
    float* dis = (float*)(chunkStart + NKB + 4);           // NN
    float* bufB = dis + NN;                                // NN*HID
    float* bufA = (float*)W;                               // aliases pedge

    auto cdiv = [](long long a, long long b) { return (int)((a + b - 1) / b); };

    // partition: bucket sort -> per-bucket (slice,dst) sort -> CSR + dis
    hist_pass<<<PB, PT, 0, stream>>>(dst4, blockHist);
    tot_pass<<<cdiv(NKB, 256), 256, 0, stream>>>(blockHist, chunkStart);
    scan_keys<<<1, NKB, 0, stream>>>(chunkStart);
    offsets_pass<<<cdiv(NKB, 256), 256, 0, stream>>>(blockHist, chunkStart);
    scatter_pass<<<PB, PT, 0, stream>>>(src4, dst4, blockHist, pedge);
    subsort<<<NB, 512, 0, stream>>>(pedge, chunkStart, pedge2, rowStart, dis);

    // conv1: bufA = (x@W1)*dis ; agg+relu+(@W3)*dis fused -> bufB
    gemm_x_w1<<<cdiv(NN, GXR), GXT, 0, stream>>>(x, W1, dis, bufA);
    agg16_all<<<NB, 1024, 0, stream>>>(pedge2, rowStart, bufA, dis, b1, W3, bufB, 0);

    // conv3: agg+relu+(@W2)*dis fused -> bufA (first 2N floats; pedge dead)
    agg16_all<<<NB, 1024, 0, stream>>>(pedge2, rowStart, bufB, dis, b3, W2, bufA, 1);

    // conv2 + log_softmax
    agg2_lsm<<<NB, 512, 0, stream>>>(pedge2, rowStart, bufA, dis, b2, out);
}

// Round 24
// 262.477 us; speedup vs baseline: 1.1670x; 1.0073x over previous
//
#include <hip/hip_runtime.h>

#define NN 200000
#define NE 5000000
#define DIN 128
#define HID 16
#define DOUT 2
#define BSZ 391          // dst-buckets of 391 nodes: 512 buckets exactly
#define NB 512           // 2 blocks/CU on 256 CUs -> full occupancy, exact balance
#define LBITS 9          // local dst index bits (391 < 512)
#define NCH 4            // src slices of 50000 nodes (3.2 MB of xs' @ HID=16, fits L2)
#define SLICE_DIV 50000
#define NK (NB * NCH)    // 2048 (bucket,slice) segments for rowStart
#define NKB 512          // stage-1 sort keys = buckets only
#define SKEYS 2048       // subsort keys: (slice<<9)|dst_local
#define PB 512           // partition grid blocks (2/CU -> 16 waves)
#define PT 512           // partition block threads
#define ECAP 9216        // subsort LDS edge cache (mean segment 9766, 94% coverage)

static_assert((size_t)NB * BSZ >= NN, "bucket coverage");
static_assert((NN - 1) / SLICE_DIV == NCH - 1, "slice count");
static_assert(NE % 8 == 0, "int4-pair edge reads");

// ---------------- stage 1: counting sort by bucket = dst/391 (512 keys) ----------------

__global__ __launch_bounds__(PT) void hist_pass(const int4* __restrict__ dst4,
                                                int* __restrict__ blockHist) {
    __shared__ int h[NKB];  // 2 KB
    for (int k = threadIdx.x; k < NKB; k += PT) h[k] = 0;
    __syncthreads();
    const int NI8 = NE / 8;
    for (int j = blockIdx.x * PT + threadIdx.x; j < NI8; j += PB * PT) {
        int4 d0 = dst4[2 * j];
        int4 d1 = dst4[2 * j + 1];
        atomicAdd(&h[d0.x / BSZ], 1);
        atomicAdd(&h[d0.y / BSZ], 1);
        atomicAdd(&h[d0.z / BSZ], 1);
        atomicAdd(&h[d0.w / BSZ], 1);
        atomicAdd(&h[d1.x / BSZ], 1);
        atomicAdd(&h[d1.y / BSZ], 1);
        atomicAdd(&h[d1.z / BSZ], 1);
        atomicAdd(&h[d1.w / BSZ], 1);
    }
    __syncthreads();
    for (int k = threadIdx.x; k < NKB; k += PT)
        blockHist[(size_t)blockIdx.x * NKB + k] = h[k];
}

__global__ __launch_bounds__(256) void tot_pass(const int* __restrict__ blockHist,
                                                int* __restrict__ chunkStart) {
    int k = blockIdx.x * 256 + threadIdx.x;
    if (k >= NKB) return;
    int s = 0;
#pragma unroll 16
    for (int b = 0; b < PB; ++b) s += blockHist[(size_t)b * NKB + k];
    chunkStart[k] = s;
}

// exclusive scan of chunkStart[0..NKB) in place (single block, 512 threads)
__global__ __launch_bounds__(NKB) void scan_keys(int* __restrict__ chunkStart) {
    __shared__ int wsum[8];
    int t = threadIdx.x;
    int lane = t & 63, w = t >> 6;
    int v = chunkStart[t];
    int inc = v;
    for (int off = 1; off < 64; off <<= 1) {
        int nb = __shfl_up(inc, off, 64);
        if (lane >= off) inc += nb;
    }
    if (lane == 63) wsum[w] = inc;
    __syncthreads();
    if (t == 0) {
        int car = 0;
#pragma unroll
        for (int i = 0; i < 8; ++i) { int u = wsum[i]; wsum[i] = car; car += u; }
    }
    __syncthreads();
    chunkStart[t] = inc - v + wsum[w];
    if (t == 0) chunkStart[NKB] = NE;
}

__global__ __launch_bounds__(256) void offsets_pass(int* __restrict__ blockHist,
                                                    const int* __restrict__ chunkStart) {
    int k = blockIdx.x * 256 + threadIdx.x;
    if (k >= NKB) return;
    int r = chunkStart[k];
#pragma unroll 8
    for (int b = 0; b < PB; ++b) {
        size_t idx = (size_t)b * NKB + k;
        int v = blockHist[idx];
        blockHist[idx] = r;
        r += v;
    }
}

__global__ __launch_bounds__(PT) void scatter_pass(const int4* __restrict__ src4,
                                                   const int4* __restrict__ dst4,
                                                   const int* __restrict__ blockHist,
                                                   unsigned* __restrict__ pedge) {
    __shared__ int cur[NKB];  // 2 KB
    for (int k = threadIdx.x; k < NKB; k += PT)
        cur[k] = blockHist[(size_t)blockIdx.x * NKB + k];
    __syncthreads();
    const int NI8 = NE / 8;
    // same per-block traversal SET as hist_pass
    for (int j = blockIdx.x * PT + threadIdx.x; j < NI8; j += PB * PT) {
        int4 s0 = src4[2 * j];
        int4 s1 = src4[2 * j + 1];
        int4 d0 = dst4[2 * j];
        int4 d1 = dst4[2 * j + 1];
        int b0 = d0.x / BSZ, b1 = d0.y / BSZ, b2 = d0.z / BSZ, b3 = d0.w / BSZ;
        int b4 = d1.x / BSZ, b5 = d1.y / BSZ, b6 = d1.z / BSZ, b7 = d1.w / BSZ;
        int p0 = atomicAdd(&cur[b0], 1);
        int p1 = atomicAdd(&cur[b1], 1);
        int p2 = atomicAdd(&cur[b2], 1);
        int p3 = atomicAdd(&cur[b3], 1);
        int p4 = atomicAdd(&cur[b4], 1);
        int p5 = atomicAdd(&cur[b5], 1);
        int p6 = atomicAdd(&cur[b6], 1);
        int p7 = atomicAdd(&cur[b7], 1);
        pedge[p0] = ((unsigned)s0.x << LBITS) | (unsigned)(d0.x - b0 * BSZ);
        pedge[p1] = ((unsigned)s0.y << LBITS) | (unsigned)(d0.y - b1 * BSZ);
        pedge[p2] = ((unsigned)s0.z << LBITS) | (unsigned)(d0.z - b2 * BSZ);
        pedge[p3] = ((unsigned)s0.w << LBITS) | (unsigned)(d0.w - b3 * BSZ);
        pedge[p4] = ((unsigned)s1.x << LBITS) | (unsigned)(d1.x - b4 * BSZ);
        pedge[p5] = ((unsigned)s1.y << LBITS) | (unsigned)(d1.y - b5 * BSZ);
        pedge[p6] = ((unsigned)s1.z << LBITS) | (unsigned)(d1.z - b6 * BSZ);
        pedge[p7] = ((unsigned)s1.w << LBITS) | (unsigned)(d1.w - b7 * BSZ);
    }
}

// ---------------- stage 2: per-bucket sort by (slice, dst_local) -> CSR (one-time) ----------------

__global__ __launch_bounds__(512) void subsort(const unsigned* __restrict__ pedge,
                                               const int* __restrict__ chunkStart,
                                               int* __restrict__ pedge2,
                                               int* __restrict__ rowStart,
                                               float* __restrict__ dis) {
    __shared__ int h[SKEYS];        // 8 KB: hist -> scan -> cur, in place
    __shared__ unsigned ebuf[ECAP]; // 36 KB edge cache
    __shared__ int wsum[8];
    int t = threadIdx.x;
    int b = blockIdx.x;
    int lane = t & 63, w = t >> 6;
    int e0 = chunkStart[b], e1 = chunkStart[b + 1];
    int n = e1 - e0;
    for (int k = t; k < SKEYS; k += 512) h[k] = 0;
    __syncthreads();
    for (int i = t; i < n; i += 512) {
        unsigned p = pedge[e0 + i];
        if (i < ECAP) ebuf[i] = p;
        int sv = (int)(p >> LBITS);
        atomicAdd(&h[(sv / SLICE_DIV) * 512 + (p & 511u)], 1);
    }
    __syncthreads();
    // degree (all slices of this local row) -> dis
    if (t < BSZ) {
        int dg = 1;  // self loop
#pragma unroll
        for (int s = 0; s < NCH; ++s) dg += h[s * 512 + t];
        int node = b * BSZ + t;
        if (node < NN) dis[node] = rsqrtf((float)dg);
    }
    // exclusive scan over 2048 bins in key order; thread t owns keys [4t, 4t+4)
    int vals[4];
    int s = 0;
#pragma unroll
    for (int j = 0; j < 4; ++j) { vals[j] = h[t * 4 + j]; s += vals[j]; }
    int inc = s;
    for (int off = 1; off < 64; off <<= 1) {
        int nb = __shfl_up(inc, off, 64);
        if (lane >= off) inc += nb;
    }
    if (lane == 63) wsum[w] = inc;
    __syncthreads();
    if (t == 0) {
        int car = 0;
#pragma unroll
        for (int i = 0; i < 8; ++i) { int u = wsum[i]; wsum[i] = car; car += u; }
    }
    __syncthreads();
    int run = inc - s + wsum[w];
#pragma unroll
    for (int j = 0; j < 4; ++j) {
        int k = t * 4 + j;
        h[k] = run;  // exclusive start within bucket (becomes cur)
        int dl = k & 511, sl = k >> 9;
        if (dl < BSZ)
            rowStart[(size_t)(b * NCH + sl) * BSZ + dl] = e0 + run;
        run += vals[j];
    }
    __syncthreads();
    for (int i = t; i < n; i += 512) {
        unsigned p = (i < ECAP) ? ebuf[i] : pedge[e0 + i];
        int sv = (int)(p >> LBITS);
        int key = (sv / SLICE_DIV) * 512 + (p & 511u);
        int pos = atomicAdd(&h[key], 1);
        pedge2[e0 + pos] = sv;
    }
    if (b == 0 && t == 0) rowStart[(size_t)NK * BSZ] = NE;
}

// ---------------- conv1 GEMM: bufA = (x @ W1) * dis ----------------

#define GXT 512
#define GXR 128
__global__ __launch_bounds__(GXT) void gemm_x_w1(const float* __restrict__ x,
                                                 const float* __restrict__ W,
                                                 const float* __restrict__ dis,
                                                 float* __restrict__ out) {
    __shared__ float w[DIN * HID];  // 8 KB
    int t = threadIdx.x;
    for (int i = t; i < DIN * HID; i += GXT) w[i] = W[i];
    __syncthreads();
    int row = blockIdx.x * GXR + (t >> 2);
    int c0 = (t & 3) * 4;
    if (row >= NN) return;
    const float4* xr = reinterpret_cast<const float4*>(x + (size_t)row * DIN);
    float ax = 0.f, ay = 0.f, az = 0.f, aw = 0.f;
#pragma unroll
    for (int k4 = 0; k4 < DIN / 4; ++k4) {
        float4 xv = xr[k4];
        float4 w0 = *reinterpret_cast<const float4*>(&w[(4 * k4 + 0) * HID + c0]);
        float4 w1 = *reinterpret_cast<const float4*>(&w[(4 * k4 + 1) * HID + c0]);
        float4 w2 = *reinterpret_cast<const float4*>(&w[(4 * k4 + 2) * HID + c0]);
        float4 w3 = *reinterpret_cast<const float4*>(&w[(4 * k4 + 3) * HID + c0]);
        ax += xv.x * w0.x + xv.y * w1.x + xv.z * w2.x + xv.w * w3.x;
        ay += xv.x * w0.y + xv.y * w1.y + xv.z * w2.y + xv.w * w3.y;
        az += xv.x * w0.z + xv.y * w1.z + xv.z * w2.z + xv.w * w3.z;
        aw += xv.x * w0.w + xv.y * w1.w + xv.z * w2.w + xv.w * w3.w;
    }
    float dd = dis[row];
    *reinterpret_cast<float4*>(&out[(size_t)row * HID + c0]) =
        make_float4(ax * dd, ay * dd, az * dd, aw * dd);
}

// ---------------- aggregation fused with next-layer GEMM (quad-shuffle) ----------------
// mode 0: out_row16 = (relu(dis*sum + bias) @ Wn[16x16]) * dis   (conv1 -> conv3 input)
// mode 1: out_row2  = (relu(dis*sum + bias) @ Wn[16x2])  * dis   (conv3 -> conv2 input)

// quad-cooperative index load: lane c4 loads pedge2[e+c4]; shuffles distribute.
// VMEM instrs per 4 edges per lane: 8 -> 5 (kernel is VMEM-issue-bound).
__device__ __forceinline__ void acc_edges(const int* __restrict__ pedge2,
                                          const float4* __restrict__ xs4,
                                          int e, int e1, int c4, float4& a) {
    for (; e + 3 < e1; e += 4) {
        int mine = pedge2[e + c4];        // one dword load per lane (4 edges/quad)
        int s0 = __shfl(mine, 0, 4);
        int s1 = __shfl(mine, 1, 4);
        int s2 = __shfl(mine, 2, 4);
        int s3 = __shfl(mine, 3, 4);
        float4 u0 = xs4[(s0 << 2) + c4];
        float4 u1 = xs4[(s1 << 2) + c4];
        float4 u2 = xs4[(s2 << 2) + c4];
        float4 u3 = xs4[(s3 << 2) + c4];
        a.x += (u0.x + u1.x) + (u2.x + u3.x);
        a.y += (u0.y + u1.y) + (u2.y + u3.y);
        a.z += (u0.z + u1.z) + (u2.z + u3.z);
        a.w += (u0.w + u1.w) + (u2.w + u3.w);
    }
    for (; e < e1; ++e) {
        float4 u = xs4[(pedge2[e] << 2) + c4];
        a.x += u.x; a.y += u.y; a.z += u.z; a.w += u.w;
    }
}

// epilogue: h = relu(dis*a + bias); then h @ Wn via quad shuffles; write *dis.
__device__ __forceinline__ void epi_store(const float* __restrict__ wl,
                                          float* __restrict__ buf,
                                          int node, int c4, const float4& a,
                                          const float4& bb, float dd, int mode) {
    float4 h;
    h.x = fmaxf(dd * a.x + bb.x, 0.f);
    h.y = fmaxf(dd * a.y + bb.y, 0.f);
    h.z = fmaxf(dd * a.z + bb.z, 0.f);
    h.w = fmaxf(dd * a.w + bb.w, 0.f);
    if (mode == 0) {
        float4 y = make_float4(0.f, 0.f, 0.f, 0.f);
        int c0 = c4 * 4;
#pragma unroll
        for (int l = 0; l < 4; ++l) {
            float h0 = __shfl(h.x, l, 4);
            float h1 = __shfl(h.y, l, 4);
            float h2 = __shfl(h.z, l, 4);
            float h3 = __shfl(h.w, l, 4);
            const float* wr = wl + (4 * l) * HID + c0;
            float4 w0 = *reinterpret_cast<const float4*>(wr);
            float4 w1 = *reinterpret_cast<const float4*>(wr + HID);
            float4 w2 = *reinterpret_cast<const float4*>(wr + 2 * HID);
            float4 w3 = *reinterpret_cast<const float4*>(wr + 3 * HID);
            y.x += h0 * w0.x + h1 * w1.x + h2 * w2.x + h3 * w3.x;
            y.y += h0 * w0.y + h1 * w1.y + h2 * w2.y + h3 * w3.y;
            y.z += h0 * w0.z + h1 * w1.z + h2 * w2.z + h3 * w3.z;
            y.w += h0 * w0.w + h1 * w1.w + h2 * w2.w + h3 * w3.w;
        }
        reinterpret_cast<float4*>(buf)[(node << 2) + c4] =
            make_float4(y.x * dd, y.y * dd, y.z * dd, y.w * dd);
    } else {
        const float* wr = wl + (4 * c4) * DOUT;
        float p0 = h.x * wr[0] + h.y * wr[2] + h.z * wr[4] + h.w * wr[6];
        float p1 = h.x * wr[1] + h.y * wr[3] + h.z * wr[5] + h.w * wr[7];
        p0 += __shfl_xor(p0, 1, 4);
        p0 += __shfl_xor(p0, 2, 4);
        p1 += __shfl_xor(p1, 1, 4);
        p1 += __shfl_xor(p1, 2, 4);
        if (c4 == 0)
            reinterpret_cast<float2*>(buf)[node] = make_float2(p0 * dd, p1 * dd);
    }
}

__global__ __launch_bounds__(1024, 8) void agg16_all(const int* __restrict__ pedge2,
                                                     const int* __restrict__ rowStart,
                                                     const float* __restrict__ xs,
                                                     const float* __restrict__ dis,
                                                     const float* __restrict__ bias,
                                                     const float* __restrict__ Wn,
                                                     float* __restrict__ buf,
                                                     int mode) {
    __shared__ float wl[HID * HID];  // 1 KB (mode 0) / 128 B used (mode 1)
    int t = threadIdx.x;
    int nw = (mode == 0) ? HID * HID : HID * DOUT;
    if (t < nw) wl[t] = Wn[t];
    __syncthreads();
    int b = blockIdx.x;
    int base = b * BSZ;
    int c4 = t & 3;
    int q = t >> 2;                         // quad 0..255
    int g0 = (q * BSZ) >> 8;                // balanced rows: 1 or 2 per quad
    int g1 = ((q + 1) * BSZ) >> 8;
    bool two = (g1 - g0) == 2;
    int n0 = base + g0, n1 = base + g0 + 1;
    bool v0 = n0 < NN;
    bool v1 = two && (n1 < NN);
    const float4* xs4 = reinterpret_cast<const float4*>(xs);
    // prefetch ALL fragment bounds (12 independent loads, one latency)
    int sA[NCH], sB[NCH], sC[NCH];
#pragma unroll
    for (int r = 0; r < NCH; ++r) {
        const int* rs = rowStart + (size_t)(b * NCH + r) * BSZ + g0;
        sA[r] = v0 ? rs[0] : 0;
        sB[r] = v0 ? rs[1] : 0;
        sC[r] = v1 ? rs[2] : 0;
    }
    float4 a0 = make_float4(0.f, 0.f, 0.f, 0.f);
    float4 a1 = a0;
    if (v0) a0 = xs4[(n0 << 2) + c4];  // self-loop term
    if (v1) a1 = xs4[(n1 << 2) + c4];
    // slice-OUTER loop: all threads in all blocks touch src window r together
#pragma unroll
    for (int r = 0; r < NCH; ++r) {
        if (v0) acc_edges(pedge2, xs4, sA[r], sB[r], c4, a0);
        if (v1) acc_edges(pedge2, xs4, sB[r], sC[r], c4, a1);
    }
    float4 bb = reinterpret_cast<const float4*>(bias)[c4];
    if (v0) epi_store(wl, buf, n0, c4, a0, bb, dis[n0], mode);
    if (v1) epi_store(wl, buf, n1, c4, a1, bb, dis[n1], mode);
}

// conv2: one thread per dst row, float2 registers, fused bias + log_softmax.
__global__ __launch_bounds__(512) void agg2_lsm(const int* __restrict__ pedge2,
                                                const int* __restrict__ rowStart,
                                                const float* __restrict__ xs,
                                                const float* __restrict__ dis,
                                                const float* __restrict__ bias,
                                                float* __restrict__ out) {
    int t = threadIdx.x;
    int b = blockIdx.x;
    if (t >= BSZ) return;
    int node = b * BSZ + t;
    if (node >= NN) return;
    const float2* xs2 = reinterpret_cast<const float2*>(xs);
    float a0 = 0.f, a1 = 0.f;
#pragma unroll
    for (int s = 0; s < NCH; ++s) {
        const int* rs = rowStart + (size_t)(b * NCH + s) * BSZ;
        int e = rs[t], e1 = rs[t + 1];
        for (; e + 3 < e1; e += 4) {
            int s0 = pedge2[e], s1 = pedge2[e + 1];
            int s2 = pedge2[e + 2], s3 = pedge2[e + 3];
            float2 v0 = xs2[s0], v1 = xs2[s1], v2 = xs2[s2], v3 = xs2[s3];
            a0 += (v0.x + v1.x) + (v2.x + v3.x);
            a1 += (v0.y + v1.y) + (v2.y + v3.y);
        }
        for (; e < e1; ++e) {
            float2 v = xs2[pedge2[e]];
            a0 += v.x; a1 += v.y;
        }
    }
    float2 sv = xs2[node];
    float d = dis[node];
    float v0 = (a0 + sv.x) * d + bias[0];
    float v1 = (a1 + sv.y) * d + bias[1];
    float m = fmaxf(v0, v1);
    float lse = m + logf(__expf(v0 - m) + __expf(v1 - m));
    reinterpret_cast<float2*>(out)[node] = make_float2(v0 - lse, v1 - lse);
}

// ---------------- launch ----------------

extern "C" void kernel_launch(void* const* d_in, const int* in_sizes, int n_in,
                              void* d_out, int out_size, void* d_ws, size_t ws_size,
                              hipStream_t stream) {
    const float* x = (const float*)d_in[0];
    const int* ei = (const int*)d_in[1];
    const float* W1 = (const float*)d_in[2];
    const float* b1 = (const float*)d_in[3];
    const float* W3 = (const float*)d_in[4];
    const float* b3 = (const float*)d_in[5];
    const float* W2 = (const float*)d_in[6];
    const float* b2 = (const float*)d_in[7];
    float* out = (float*)d_out;

    const int4* src4 = (const int4*)ei;             // edge_index[0], 16B-aligned
    const int4* dst4 = (const int4*)(ei + NE);      // edge_index[1]

    // workspace layout (~58 MB). bufA aliases pedge (dead after subsort).
    int* W = (int*)d_ws;
    unsigned* pedge = (unsigned*)W;                        // NE
    int* pedge2 = W + NE;                                  // NE
    int* rowStart = W + 2 * (size_t)NE;                    // NK*BSZ + 4
    int* blockHist = rowStart + (size_t)NK * BSZ + 4;      // PB*NKB
    int* chunkStart = blockHist + (size_t)PB * NKB;        // NKB + 4
    float* dis = (float*)(chunkStart + NKB + 4);           // NN
    float* bufB = dis + NN;                                // NN*HID
    float* bufA = (float*)W;                               // aliases pedge

    auto cdiv = [](long long a, long long b) { return (int)((a + b - 1) / b); };

    // partition: bucket sort -> per-bucket (slice,dst) sort -> CSR + dis
    hist_pass<<<PB, PT, 0, stream>>>(dst4, blockHist);
    tot_pass<<<cdiv(NKB, 256), 256, 0, stream>>>(blockHist, chunkStart);
    scan_keys<<<1, NKB, 0, stream>>>(chunkStart);
    offsets_pass<<<cdiv(NKB, 256), 256, 0, stream>>>(blockHist, chunkStart);
    scatter_pass<<<PB, PT, 0, stream>>>(src4, dst4, blockHist, pedge);
    subsort<<<NB, 512, 0, stream>>>(pedge, chunkStart, pedge2, rowStart, dis);

    // conv1: bufA = (x@W1)*dis ; agg+relu+(@W3)*dis fused -> bufB
    gemm_x_w1<<<cdiv(NN, GXR), GXT, 0, stream>>>(x, W1, dis, bufA);
    agg16_all<<<NB, 1024, 0, stream>>>(pedge2, rowStart, bufA, dis, b1, W3, bufB, 0);

    // conv3: agg+relu+(@W2)*dis fused -> bufA (first 2N floats; pedge dead)
    agg16_all<<<NB, 1024, 0, stream>>>(pedge2, rowStart, bufB, dis, b3, W2, bufA, 1);

    // conv2 + log_softmax
    agg2_lsm<<<NB, 512, 0, stream>>>(pedge2, rowStart, bufA, dis, b2, out);
}